// Round 2
// baseline (595.314 us; speedup 1.0000x reference)
//
#include <hip/hip_runtime.h>

// BoxCrossCategoryLoss: streaming row-wise loss over 6 x (N,2) f32 arrays.
// int index inputs are unused by the reference (recipes are constants).
//
// R5 (resubmit; previous round was a container-acquire infra failure, no
// kernel signal): copy-free ring-of-3 prefetch. R4's VGPR_Count=56 proved
// its "double buffer" collapsed (48 data regs + ~30 temps can't fit in 56):
// the cur=nxt copy rotation let the allocator serialize load->wait->compute,
// leaving ~1 KB/wave in flight -> 2.87 TB/s delivered (roofline ~6.3).
// The ring has no register copies to coalesce: three named buffers X/Y/Z,
// each loaded 2 compute-phases (~1900 cy) before its use, sched_barrier(0)
// fencing each load group. Expect VGPR ~100-120 and vmcnt(12) waits.

#define LOG2E 1.4426950408889634f
#define LN2   0.6931471805599453f

__device__ __forceinline__ float fexp2(float x) { return __builtin_amdgcn_exp2f(x); }
__device__ __forceinline__ float flog2(float x) { return __builtin_amdgcn_logf(x); }
__device__ __forceinline__ float relu_(float x) { return fmaxf(x, 0.0f); }

// Per-row loss in LOG2 UNITS. Raw natural-log inputs (strictly negative).
__device__ __forceinline__ float row_loss_l2(
    float a0, float a1, float b0, float b1,
    float c0, float c1, float d0, float d1,
    float e0, float e1, float f0, float f1)
{
    // scaled inputs (log2 units) — also the exp2 arguments
    float a0s = a0 * LOG2E, a1s = a1 * LOG2E;
    float b0s = b0 * LOG2E, b1s = b1 * LOG2E;
    float c0s = c0 * LOG2E, c1s = c1 * LOG2E;
    float d0s = d0 * LOG2E, d1s = d1 * LOG2E;
    float e0s = e0 * LOG2E, e1s = e1 * LOG2E;
    float f0s = f0 * LOG2E, f1s = f1 * LOG2E;

    // u = exp(x) via hardware exp2; w = 1 - u
    float ua0 = fexp2(a0s), ub0 = fexp2(b0s), uc0 = fexp2(c0s), ud0 = fexp2(d0s);
    float ue0 = fexp2(e0s), uf0 = fexp2(f0s);
    float ua1 = fexp2(a1s), ub1 = fexp2(b1s), uc1 = fexp2(c1s), ud1 = fexp2(d1s);
    float ue1 = fexp2(e1s), uf1 = fexp2(f1s);

    float wa0 = 1.0f - ua0, wb0 = 1.0f - ub0, wc0 = 1.0f - uc0, wd0 = 1.0f - ud0;
    float we0 = 1.0f - ue0, wf0 = 1.0f - uf0;
    float wa1 = 1.0f - ua1, wb1 = 1.0f - ub1, wc1 = 1.0f - uc1, wd1 = 1.0f - ud1;
    float we1 = 1.0f - ue1, wf1 = 1.0f - uf1;

    // l = log2(1 - exp(x)) via hardware log2 (10 needed individually)
    float la0 = flog2(wa0), lb0 = flog2(wb0), lc0 = flog2(wc0), ld0 = flog2(wd0);
    float la1 = flog2(wa1), lb1 = flog2(wb1), lc1 = flog2(wc1), ld1 = flog2(wd1);
    float le1 = flog2(we1), lf1 = flog2(wf1);

    // LACk = log1mexp(pAC[k][:,0]) in log2 units:
    float LAC0 = flog2(fmaf(-ue0, wf0, 1.0f));
    float LAC1 = flog2(fmaf(-we0, uf0, 1.0f));
    float LAC2 = flog2(fmaf(-ue0, uf0, 1.0f));

    // p[k] = [v1+l2, l1+v2, v1+v2, l1+l2]  (log2 units)
    float AB00 = a0s + lb0, AB10 = la0 + b0s, AB20 = a0s + b0s;
    float AB01 = a1s + lb1, AB11 = la1 + b1s, AB21 = a1s + b1s, AB31 = la1 + lb1;
    float BC00 = c0s + ld0, BC10 = lc0 + d0s, BC20 = c0s + d0s;
    float BC01 = c1s + ld1, BC11 = lc1 + d1s, BC21 = c1s + d1s, BC31 = lc1 + ld1;
    float AC01 = e1s + lf1, AC11 = le1 + f1s, AC21 = e1s + f1s, AC31 = le1 + lf1;

    // 14 unique AB+BC sums shared across the 36 terms.
    float s1  = AB00 + BC01, s2  = AB00 + BC21, s3  = AB10 + BC11, s4  = AB10 + BC21;
    float s5  = AB20 + BC01, s6  = AB20 + BC11, s7  = AB20 + BC21, s8  = AB20 + BC31;
    float s9  = AB01 + BC00, s10 = AB01 + BC20, s11 = AB11 + BC10, s12 = AB11 + BC20;
    float s13 = AB21 + BC20, s14 = AB31 + BC20;

    // Two independent accumulator chains for add ILP.
    float p = 0.0f, q = 0.0f;
    // LOSS_RECIPE (14 terms)
    p += relu_(s1 - AC01) + relu_(s2 - AC01) + relu_(s3 - AC11) + relu_(s4 - AC11);
    q += relu_(s5 - AC01) + relu_(s6 - AC11) + relu_(s7 - AC21) + relu_(s8 - AC31);
    p += relu_(s9 - AC01) + relu_(s10 - AC01) + relu_(s11 - AC11) + relu_(s12 - AC11);
    q += relu_(s13 - AC21) + relu_(s14 - AC31);
    // NEG_LOSS_RECIPE (22 terms)
    p += relu_(s1 - LAC1) + relu_(s1 - LAC2) + relu_(s2 - LAC1) + relu_(s2 - LAC2);
    q += relu_(s3 - LAC0) + relu_(s3 - LAC2) + relu_(s4 - LAC0) + relu_(s4 - LAC2);
    p += relu_(s5 - LAC1) + relu_(s5 - LAC2) + relu_(s6 - LAC0) + relu_(s6 - LAC2);
    q += relu_(s9 - LAC1) + relu_(s9 - LAC2) + relu_(s10 - LAC1) + relu_(s10 - LAC2);
    p += relu_(s11 - LAC0) + relu_(s11 - LAC2) + relu_(s12 - LAC0) + relu_(s12 - LAC2);
    q += relu_(s8 - LAC2) + relu_(s14 - LAC2);
    return p + q;  // log2 units
}

struct Seg {
    float4 ab, ba, bc, cb, ac, ca;
};

__device__ __forceinline__ float pair_loss(const Seg& s)
{
    return row_loss_l2(s.ab.x, s.ab.y, s.ba.x, s.ba.y, s.bc.x, s.bc.y,
                       s.cb.x, s.cb.y, s.ac.x, s.ac.y, s.ca.x, s.ca.y)
         + row_loss_l2(s.ab.z, s.ab.w, s.ba.z, s.ba.w, s.bc.z, s.bc.w,
                       s.cb.z, s.cb.w, s.ac.z, s.ac.w, s.ca.z, s.ca.w);
}

__global__ __launch_bounds__(256, 4) void box_loss_kernel(
    const float* __restrict__ AB, const float* __restrict__ BA,
    const float* __restrict__ BC, const float* __restrict__ CB,
    const float* __restrict__ AC, const float* __restrict__ CA,
    float* __restrict__ out, long nElems)
{
    const long nE = nElems;
    const long T = (long)gridDim.x * blockDim.x * 4;       // tap stride (elems)
    long t = ((long)blockIdx.x * blockDim.x + threadIdx.x) * 4;

    // Taps per thread (uniform across grid); ring-of-3 rounds.
    const int nT = (int)((nE + T - 1) / T);
    const int rounds = (nT + 2) / 3;

    // Branch-free bounds: clamp OOB address to 0 (valid data), zero the mask.
    #define LOAD_SEG(dst, msk, base)                        \
        do {                                                \
            bool v_ = ((base) + 4) <= nE;                   \
            long a_ = v_ ? (base) : 0;                      \
            (msk) = v_ ? 1.0f : 0.0f;                       \
            (dst).ab = *(const float4*)(AB + a_);           \
            (dst).ba = *(const float4*)(BA + a_);           \
            (dst).bc = *(const float4*)(BC + a_);           \
            (dst).cb = *(const float4*)(CB + a_);           \
            (dst).ac = *(const float4*)(AC + a_);           \
            (dst).ca = *(const float4*)(CA + a_);           \
        } while (0)

    Seg X, Y, Z;
    float mX, mY, mZ;

    // Prologue: fill the ring — 18 loads (18 KB/wave) issued back-to-back.
    LOAD_SEG(X, mX, t); t += T;
    LOAD_SEG(Y, mY, t); t += T;
    LOAD_SEG(Z, mZ, t); t += T;
    __builtin_amdgcn_sched_barrier(0);

    float acc = 0.0f;
    // Steady state: consume one buffer, immediately re-issue its 6 loads for
    // a tap 3 slots ahead. Each buffer's load->use distance is 2 full compute
    // phases; compiler should wait vmcnt(12) per slot, never vmcnt(0).
    for (int r = 0; r < rounds - 1; ++r) {
        acc += mX * pair_loss(X);
        LOAD_SEG(X, mX, t); t += T;
        __builtin_amdgcn_sched_barrier(0);

        acc += mY * pair_loss(Y);
        LOAD_SEG(Y, mY, t); t += T;
        __builtin_amdgcn_sched_barrier(0);

        acc += mZ * pair_loss(Z);
        LOAD_SEG(Z, mZ, t); t += T;
        __builtin_amdgcn_sched_barrier(0);
    }
    // Epilogue: drain the ring (no further loads, no junk traffic).
    acc += mX * pair_loss(X);
    acc += mY * pair_loss(Y);
    acc += mZ * pair_loss(Z);
    #undef LOAD_SEG

    acc *= LN2;  // convert log2-unit total back to natural units

    // wave64 butterfly reduce
    #pragma unroll
    for (int off = 32; off > 0; off >>= 1)
        acc += __shfl_down(acc, off, 64);

    __shared__ float wsum[4];
    const int lane = threadIdx.x & 63;
    const int wid  = threadIdx.x >> 6;
    if (lane == 0) wsum[wid] = acc;
    __syncthreads();
    if (threadIdx.x == 0) {
        float s = wsum[0] + wsum[1] + wsum[2] + wsum[3];
        atomicAdd(out, s);
    }
}

extern "C" void kernel_launch(void* const* d_in, const int* in_sizes, int n_in,
                              void* d_out, int out_size, void* d_ws, size_t ws_size,
                              hipStream_t stream) {
    const float* AB = (const float*)d_in[0];  // vol_AB
    const float* BA = (const float*)d_in[1];  // vol_BA
    const float* BC = (const float*)d_in[2];  // vol_BC
    const float* CB = (const float*)d_in[3];  // vol_CB
    const float* AC = (const float*)d_in[4];  // vol_AC
    const float* CA = (const float*)d_in[5];  // vol_CA
    // d_in[6..8] (xy/yz/xz rel ids) are unused by the reference.

    const long nElems = in_sizes[0];  // N*2
    const int block = 256;
    // 2816 = 11 blocks/CU exactly (balanced tail); taps/thread = 6 for
    // N*2 = 16M -> exactly 2 ring rounds, no junk slots.
    const int grid = 2816;

    // d_out is poisoned with 0xAA before every timed launch — zero it.
    hipMemsetAsync(d_out, 0, (size_t)out_size * sizeof(float), stream);
    box_loss_kernel<<<grid, block, 0, stream>>>(AB, BA, BC, CB, AC, CA,
                                                (float*)d_out, nElems);
}

// Round 3
// 593.238 us; speedup vs baseline: 1.0035x; 1.0035x over previous
//
#include <hip/hip_runtime.h>

// BoxCrossCategoryLoss: streaming row-wise loss over 6 x (N,2) f32 arrays.
// int index inputs are unused by the reference (recipes are constants).
//
// R6: ring-of-2 prefetch, zero register copies, 32-bit addressing.
// History: R4 (VGPR=56) collapsed its double buffer -> serialized
// load/compute, 2.87 TB/s delivered. R5's ring-of-3 needed ~130 VGPRs,
// blew the launch_bounds(256,4) cap of 128 -> allocator clamped to 64 and
// spilled (WRITE_SIZE 64KB -> 557MB, dur 2x worse) BUT sustained 3.7 TB/s
// HBM-side, proving the decoupled-pipeline structure works. R6 shrinks the
// ring to depth 2 (~90 VGPRs incl. temps): fits the 128 cap, 16 waves/CU,
// ~6KB/wave in flight for a full compute phase -> ~96KB/CU average
// in-flight vs ~20KB needed to saturate HBM at ~2000cy latency.

#define LOG2E 1.4426950408889634f
#define LN2   0.6931471805599453f

__device__ __forceinline__ float fexp2(float x) { return __builtin_amdgcn_exp2f(x); }
__device__ __forceinline__ float flog2(float x) { return __builtin_amdgcn_logf(x); }
__device__ __forceinline__ float relu_(float x) { return fmaxf(x, 0.0f); }

// Per-row loss in LOG2 UNITS. Raw natural-log inputs (strictly negative).
__device__ __forceinline__ float row_loss_l2(
    float a0, float a1, float b0, float b1,
    float c0, float c1, float d0, float d1,
    float e0, float e1, float f0, float f1)
{
    // scaled inputs (log2 units) — also the exp2 arguments
    float a0s = a0 * LOG2E, a1s = a1 * LOG2E;
    float b0s = b0 * LOG2E, b1s = b1 * LOG2E;
    float c0s = c0 * LOG2E, c1s = c1 * LOG2E;
    float d0s = d0 * LOG2E, d1s = d1 * LOG2E;
    float e0s = e0 * LOG2E, e1s = e1 * LOG2E;
    float f0s = f0 * LOG2E, f1s = f1 * LOG2E;

    // u = exp(x) via hardware exp2; w = 1 - u
    float ua0 = fexp2(a0s), ub0 = fexp2(b0s), uc0 = fexp2(c0s), ud0 = fexp2(d0s);
    float ue0 = fexp2(e0s), uf0 = fexp2(f0s);
    float ua1 = fexp2(a1s), ub1 = fexp2(b1s), uc1 = fexp2(c1s), ud1 = fexp2(d1s);
    float ue1 = fexp2(e1s), uf1 = fexp2(f1s);

    float wa0 = 1.0f - ua0, wb0 = 1.0f - ub0, wc0 = 1.0f - uc0, wd0 = 1.0f - ud0;
    float we0 = 1.0f - ue0, wf0 = 1.0f - uf0;
    float wa1 = 1.0f - ua1, wb1 = 1.0f - ub1, wc1 = 1.0f - uc1, wd1 = 1.0f - ud1;
    float we1 = 1.0f - ue1, wf1 = 1.0f - uf1;

    // l = log2(1 - exp(x)) via hardware log2 (10 needed individually)
    float la0 = flog2(wa0), lb0 = flog2(wb0), lc0 = flog2(wc0), ld0 = flog2(wd0);
    float la1 = flog2(wa1), lb1 = flog2(wb1), lc1 = flog2(wc1), ld1 = flog2(wd1);
    float le1 = flog2(we1), lf1 = flog2(wf1);

    // LACk = log1mexp(pAC[k][:,0]) in log2 units:
    float LAC0 = flog2(fmaf(-ue0, wf0, 1.0f));
    float LAC1 = flog2(fmaf(-we0, uf0, 1.0f));
    float LAC2 = flog2(fmaf(-ue0, uf0, 1.0f));

    // p[k] = [v1+l2, l1+v2, v1+v2, l1+l2]  (log2 units)
    float AB00 = a0s + lb0, AB10 = la0 + b0s, AB20 = a0s + b0s;
    float AB01 = a1s + lb1, AB11 = la1 + b1s, AB21 = a1s + b1s, AB31 = la1 + lb1;
    float BC00 = c0s + ld0, BC10 = lc0 + d0s, BC20 = c0s + d0s;
    float BC01 = c1s + ld1, BC11 = lc1 + d1s, BC21 = c1s + d1s, BC31 = lc1 + ld1;
    float AC01 = e1s + lf1, AC11 = le1 + f1s, AC21 = e1s + f1s, AC31 = le1 + lf1;

    // 14 unique AB+BC sums shared across the 36 terms.
    float s1  = AB00 + BC01, s2  = AB00 + BC21, s3  = AB10 + BC11, s4  = AB10 + BC21;
    float s5  = AB20 + BC01, s6  = AB20 + BC11, s7  = AB20 + BC21, s8  = AB20 + BC31;
    float s9  = AB01 + BC00, s10 = AB01 + BC20, s11 = AB11 + BC10, s12 = AB11 + BC20;
    float s13 = AB21 + BC20, s14 = AB31 + BC20;

    // Two independent accumulator chains for add ILP.
    float p = 0.0f, q = 0.0f;
    // LOSS_RECIPE (14 terms)
    p += relu_(s1 - AC01) + relu_(s2 - AC01) + relu_(s3 - AC11) + relu_(s4 - AC11);
    q += relu_(s5 - AC01) + relu_(s6 - AC11) + relu_(s7 - AC21) + relu_(s8 - AC31);
    p += relu_(s9 - AC01) + relu_(s10 - AC01) + relu_(s11 - AC11) + relu_(s12 - AC11);
    q += relu_(s13 - AC21) + relu_(s14 - AC31);
    // NEG_LOSS_RECIPE (22 terms)
    p += relu_(s1 - LAC1) + relu_(s1 - LAC2) + relu_(s2 - LAC1) + relu_(s2 - LAC2);
    q += relu_(s3 - LAC0) + relu_(s3 - LAC2) + relu_(s4 - LAC0) + relu_(s4 - LAC2);
    p += relu_(s5 - LAC1) + relu_(s5 - LAC2) + relu_(s6 - LAC0) + relu_(s6 - LAC2);
    q += relu_(s9 - LAC1) + relu_(s9 - LAC2) + relu_(s10 - LAC1) + relu_(s10 - LAC2);
    p += relu_(s11 - LAC0) + relu_(s11 - LAC2) + relu_(s12 - LAC0) + relu_(s12 - LAC2);
    q += relu_(s8 - LAC2) + relu_(s14 - LAC2);
    return p + q;  // log2 units
}

struct Seg {
    float4 ab, ba, bc, cb, ac, ca;
};

__device__ __forceinline__ float pair_loss(const Seg& s)
{
    return row_loss_l2(s.ab.x, s.ab.y, s.ba.x, s.ba.y, s.bc.x, s.bc.y,
                       s.cb.x, s.cb.y, s.ac.x, s.ac.y, s.ca.x, s.ca.y)
         + row_loss_l2(s.ab.z, s.ab.w, s.ba.z, s.ba.w, s.bc.z, s.bc.w,
                       s.cb.z, s.cb.w, s.ac.z, s.ac.w, s.ca.z, s.ca.w);
}

__global__ __launch_bounds__(256, 4) void box_loss_kernel(
    const float* __restrict__ AB, const float* __restrict__ BA,
    const float* __restrict__ BC, const float* __restrict__ CB,
    const float* __restrict__ AC, const float* __restrict__ CA,
    float* __restrict__ out, unsigned nElems)
{
    const unsigned nE = nElems;
    // 32-bit element offsets (arrays are 64 MB; max offset ~17M floats):
    // lets the compiler use saddr-form global_load_dwordx4 (SGPR base +
    // 32-bit VGPR offset) instead of per-array 64-bit VGPR address pairs.
    const unsigned T = (unsigned)gridDim.x * blockDim.x * 4u;  // tap stride
    unsigned t = ((unsigned)blockIdx.x * blockDim.x + threadIdx.x) * 4u;

    const unsigned nT = (nE + T - 1u) / T;      // taps per thread
    const int pairs = (int)((nT + 1u) / 2u);    // processed taps = 2*pairs

    // Branch-free bounds: clamp OOB offset to 0 (valid data), zero the mask.
    #define LOAD_SEG(dst, msk, base)                        \
        do {                                                \
            bool v_ = ((base) + 4u) <= nE;                  \
            unsigned a_ = v_ ? (base) : 0u;                 \
            (msk) = v_ ? 1.0f : 0.0f;                       \
            (dst).ab = *(const float4*)(AB + a_);           \
            (dst).ba = *(const float4*)(BA + a_);           \
            (dst).bc = *(const float4*)(BC + a_);           \
            (dst).cb = *(const float4*)(CB + a_);           \
            (dst).ac = *(const float4*)(AC + a_);           \
            (dst).ca = *(const float4*)(CA + a_);           \
        } while (0)

    Seg X, Y;
    float mX, mY;

    // Prologue: fill both ring slots (12 dwordx4 loads, 12 KB/wave in flight).
    LOAD_SEG(X, mX, t); t += T;
    LOAD_SEG(Y, mY, t); t += T;
    __builtin_amdgcn_sched_barrier(0);

    float acc = 0.0f;
    // Steady state: consume one slot, immediately re-issue its 6 loads for
    // the tap 2 slots ahead; sched_barrier(0) pins the issue above the next
    // slot's compute so each slot's load->use distance is one full compute
    // phase (compiler should wait vmcnt(6), never vmcnt(0)).
    for (int r = 0; r < pairs - 1; ++r) {
        acc += mX * pair_loss(X);
        LOAD_SEG(X, mX, t); t += T;
        __builtin_amdgcn_sched_barrier(0);

        acc += mY * pair_loss(Y);
        LOAD_SEG(Y, mY, t); t += T;
        __builtin_amdgcn_sched_barrier(0);
    }
    // Epilogue: drain the ring (no further loads, no junk traffic).
    acc += mX * pair_loss(X);
    acc += mY * pair_loss(Y);
    #undef LOAD_SEG

    acc *= LN2;  // convert log2-unit total back to natural units

    // wave64 butterfly reduce
    #pragma unroll
    for (int off = 32; off > 0; off >>= 1)
        acc += __shfl_down(acc, off, 64);

    __shared__ float wsum[4];
    const int lane = threadIdx.x & 63;
    const int wid  = threadIdx.x >> 6;
    if (lane == 0) wsum[wid] = acc;
    __syncthreads();
    if (threadIdx.x == 0) {
        float s = wsum[0] + wsum[1] + wsum[2] + wsum[3];
        atomicAdd(out, s);
    }
}

extern "C" void kernel_launch(void* const* d_in, const int* in_sizes, int n_in,
                              void* d_out, int out_size, void* d_ws, size_t ws_size,
                              hipStream_t stream) {
    const float* AB = (const float*)d_in[0];  // vol_AB
    const float* BA = (const float*)d_in[1];  // vol_BA
    const float* BC = (const float*)d_in[2];  // vol_BC
    const float* CB = (const float*)d_in[3];  // vol_CB
    const float* AC = (const float*)d_in[4];  // vol_AC
    const float* CA = (const float*)d_in[5];  // vol_CA
    // d_in[6..8] (xy/yz/xz rel ids) are unused by the reference.

    const unsigned nElems = (unsigned)in_sizes[0];  // N*2 = 16M
    const int block = 256;
    // grid 1024 = exactly 4 resident blocks/CU at VGPR 65..128 (16 waves/CU).
    // 16 taps/thread -> 8 ring rounds: deep steady state, amortized fill/drain.
    const int grid = 1024;

    // d_out is poisoned with 0xAA before every timed launch — zero it.
    hipMemsetAsync(d_out, 0, (size_t)out_size * sizeof(float), stream);
    box_loss_kernel<<<grid, block, 0, stream>>>(AB, BA, BC, CB, AC, CA,
                                                (float*)d_out, nElems);
}

// Round 4
// 440.278 us; speedup vs baseline: 1.3521x; 1.3474x over previous
//
#include <hip/hip_runtime.h>

// BoxCrossCategoryLoss: streaming row-wise loss over 6 x (N,2) f32 arrays.
// int index inputs are unused by the reference (recipes are constants).
//
// R7: same ring-of-2 pipeline as R6, but with the register BUDGET fixed.
// Evidence trail: R5 (ring-3) and R6 (ring-2) both came back at exactly
// VGPR=64 with ~600 MB/dispatch of scratch spill, despite launch_bounds
// (256,4) nominally allowing 128 VGPRs. Two different structures pinned at
// the 8-waves/EU register boundary with voluntary catastrophic spill =>
// the allocator's effective min-waves/EU is 8, not 4, on this toolchain.
// Fix: __launch_bounds__(256) only (flat work-group size), plus explicit
// amdgpu_waves_per_eu(2,5): min=2 -> RA budget 256 VGPRs (pressure ~100,
// no spill), max=5 -> occupancy heuristics can't target the 64-reg point.
// Grid 2560 (10 blocks/CU, 8 taps/thread): staggered completion tolerates
// whatever residency (3-5 blocks/CU) the final VGPR count produces.

#define LOG2E 1.4426950408889634f
#define LN2   0.6931471805599453f

__device__ __forceinline__ float fexp2(float x) { return __builtin_amdgcn_exp2f(x); }
__device__ __forceinline__ float flog2(float x) { return __builtin_amdgcn_logf(x); }
__device__ __forceinline__ float relu_(float x) { return fmaxf(x, 0.0f); }

// Per-row loss in LOG2 UNITS. Raw natural-log inputs (strictly negative).
__device__ __forceinline__ float row_loss_l2(
    float a0, float a1, float b0, float b1,
    float c0, float c1, float d0, float d1,
    float e0, float e1, float f0, float f1)
{
    // scaled inputs (log2 units) — also the exp2 arguments
    float a0s = a0 * LOG2E, a1s = a1 * LOG2E;
    float b0s = b0 * LOG2E, b1s = b1 * LOG2E;
    float c0s = c0 * LOG2E, c1s = c1 * LOG2E;
    float d0s = d0 * LOG2E, d1s = d1 * LOG2E;
    float e0s = e0 * LOG2E, e1s = e1 * LOG2E;
    float f0s = f0 * LOG2E, f1s = f1 * LOG2E;

    // u = exp(x) via hardware exp2; w = 1 - u
    float ua0 = fexp2(a0s), ub0 = fexp2(b0s), uc0 = fexp2(c0s), ud0 = fexp2(d0s);
    float ue0 = fexp2(e0s), uf0 = fexp2(f0s);
    float ua1 = fexp2(a1s), ub1 = fexp2(b1s), uc1 = fexp2(c1s), ud1 = fexp2(d1s);
    float ue1 = fexp2(e1s), uf1 = fexp2(f1s);

    float wa0 = 1.0f - ua0, wb0 = 1.0f - ub0, wc0 = 1.0f - uc0, wd0 = 1.0f - ud0;
    float we0 = 1.0f - ue0, wf0 = 1.0f - uf0;
    float wa1 = 1.0f - ua1, wb1 = 1.0f - ub1, wc1 = 1.0f - uc1, wd1 = 1.0f - ud1;
    float we1 = 1.0f - ue1, wf1 = 1.0f - uf1;

    // l = log2(1 - exp(x)) via hardware log2 (10 needed individually)
    float la0 = flog2(wa0), lb0 = flog2(wb0), lc0 = flog2(wc0), ld0 = flog2(wd0);
    float la1 = flog2(wa1), lb1 = flog2(wb1), lc1 = flog2(wc1), ld1 = flog2(wd1);
    float le1 = flog2(we1), lf1 = flog2(wf1);

    // LACk = log1mexp(pAC[k][:,0]) in log2 units:
    float LAC0 = flog2(fmaf(-ue0, wf0, 1.0f));
    float LAC1 = flog2(fmaf(-we0, uf0, 1.0f));
    float LAC2 = flog2(fmaf(-ue0, uf0, 1.0f));

    // p[k] = [v1+l2, l1+v2, v1+v2, l1+l2]  (log2 units)
    float AB00 = a0s + lb0, AB10 = la0 + b0s, AB20 = a0s + b0s;
    float AB01 = a1s + lb1, AB11 = la1 + b1s, AB21 = a1s + b1s, AB31 = la1 + lb1;
    float BC00 = c0s + ld0, BC10 = lc0 + d0s, BC20 = c0s + d0s;
    float BC01 = c1s + ld1, BC11 = lc1 + d1s, BC21 = c1s + d1s, BC31 = lc1 + ld1;
    float AC01 = e1s + lf1, AC11 = le1 + f1s, AC21 = e1s + f1s, AC31 = le1 + lf1;

    // 14 unique AB+BC sums shared across the 36 terms.
    float s1  = AB00 + BC01, s2  = AB00 + BC21, s3  = AB10 + BC11, s4  = AB10 + BC21;
    float s5  = AB20 + BC01, s6  = AB20 + BC11, s7  = AB20 + BC21, s8  = AB20 + BC31;
    float s9  = AB01 + BC00, s10 = AB01 + BC20, s11 = AB11 + BC10, s12 = AB11 + BC20;
    float s13 = AB21 + BC20, s14 = AB31 + BC20;

    // Two independent accumulator chains for add ILP.
    float p = 0.0f, q = 0.0f;
    // LOSS_RECIPE (14 terms)
    p += relu_(s1 - AC01) + relu_(s2 - AC01) + relu_(s3 - AC11) + relu_(s4 - AC11);
    q += relu_(s5 - AC01) + relu_(s6 - AC11) + relu_(s7 - AC21) + relu_(s8 - AC31);
    p += relu_(s9 - AC01) + relu_(s10 - AC01) + relu_(s11 - AC11) + relu_(s12 - AC11);
    q += relu_(s13 - AC21) + relu_(s14 - AC31);
    // NEG_LOSS_RECIPE (22 terms)
    p += relu_(s1 - LAC1) + relu_(s1 - LAC2) + relu_(s2 - LAC1) + relu_(s2 - LAC2);
    q += relu_(s3 - LAC0) + relu_(s3 - LAC2) + relu_(s4 - LAC0) + relu_(s4 - LAC2);
    p += relu_(s5 - LAC1) + relu_(s5 - LAC2) + relu_(s6 - LAC0) + relu_(s6 - LAC2);
    q += relu_(s9 - LAC1) + relu_(s9 - LAC2) + relu_(s10 - LAC1) + relu_(s10 - LAC2);
    p += relu_(s11 - LAC0) + relu_(s11 - LAC2) + relu_(s12 - LAC0) + relu_(s12 - LAC2);
    q += relu_(s8 - LAC2) + relu_(s14 - LAC2);
    return p + q;  // log2 units
}

struct Seg {
    float4 ab, ba, bc, cb, ac, ca;
};

__device__ __forceinline__ float pair_loss(const Seg& s)
{
    return row_loss_l2(s.ab.x, s.ab.y, s.ba.x, s.ba.y, s.bc.x, s.bc.y,
                       s.cb.x, s.cb.y, s.ac.x, s.ac.y, s.ca.x, s.ca.y)
         + row_loss_l2(s.ab.z, s.ab.w, s.ba.z, s.ba.w, s.bc.z, s.bc.w,
                       s.cb.z, s.cb.w, s.ac.z, s.ac.w, s.ca.z, s.ca.w);
}

__global__ __launch_bounds__(256)
__attribute__((amdgpu_waves_per_eu(2, 5)))
void box_loss_kernel(
    const float* __restrict__ AB, const float* __restrict__ BA,
    const float* __restrict__ BC, const float* __restrict__ CB,
    const float* __restrict__ AC, const float* __restrict__ CA,
    float* __restrict__ out, unsigned nElems)
{
    const unsigned nE = nElems;
    // 32-bit element offsets (arrays are 64 MB; max offset ~17M floats):
    // saddr-form global_load_dwordx4 (SGPR base + 32-bit VGPR offset).
    const unsigned T = (unsigned)gridDim.x * blockDim.x * 4u;  // tap stride
    unsigned t = ((unsigned)blockIdx.x * blockDim.x + threadIdx.x) * 4u;

    const unsigned nT = (nE + T - 1u) / T;      // taps per thread
    const int pairs = (int)((nT + 1u) / 2u);    // processed taps = 2*pairs

    // Branch-free bounds: clamp OOB offset to 0 (valid data), zero the mask.
    #define LOAD_SEG(dst, msk, base)                        \
        do {                                                \
            bool v_ = ((base) + 4u) <= nE;                  \
            unsigned a_ = v_ ? (base) : 0u;                 \
            (msk) = v_ ? 1.0f : 0.0f;                       \
            (dst).ab = *(const float4*)(AB + a_);           \
            (dst).ba = *(const float4*)(BA + a_);           \
            (dst).bc = *(const float4*)(BC + a_);           \
            (dst).cb = *(const float4*)(CB + a_);           \
            (dst).ac = *(const float4*)(AC + a_);           \
            (dst).ca = *(const float4*)(CA + a_);           \
        } while (0)

    Seg X, Y;
    float mX, mY;

    // Prologue: fill both ring slots (12 dwordx4 loads, 12 KB/wave in flight).
    LOAD_SEG(X, mX, t); t += T;
    LOAD_SEG(Y, mY, t); t += T;
    __builtin_amdgcn_sched_barrier(0);

    float acc = 0.0f;
    // Steady state: consume one slot, immediately re-issue its 6 loads for
    // the tap 2 slots ahead; sched_barrier(0) pins the issue above the next
    // slot's compute so each slot's load->use distance is one full compute
    // phase (compiler should wait vmcnt(6), never vmcnt(0)).
    for (int r = 0; r < pairs - 1; ++r) {
        acc += mX * pair_loss(X);
        LOAD_SEG(X, mX, t); t += T;
        __builtin_amdgcn_sched_barrier(0);

        acc += mY * pair_loss(Y);
        LOAD_SEG(Y, mY, t); t += T;
        __builtin_amdgcn_sched_barrier(0);
    }
    // Epilogue: drain the ring (no further loads, no junk traffic).
    acc += mX * pair_loss(X);
    acc += mY * pair_loss(Y);
    #undef LOAD_SEG

    acc *= LN2;  // convert log2-unit total back to natural units

    // wave64 butterfly reduce
    #pragma unroll
    for (int off = 32; off > 0; off >>= 1)
        acc += __shfl_down(acc, off, 64);

    __shared__ float wsum[4];
    const int lane = threadIdx.x & 63;
    const int wid  = threadIdx.x >> 6;
    if (lane == 0) wsum[wid] = acc;
    __syncthreads();
    if (threadIdx.x == 0) {
        float s = wsum[0] + wsum[1] + wsum[2] + wsum[3];
        atomicAdd(out, s);
    }
}

extern "C" void kernel_launch(void* const* d_in, const int* in_sizes, int n_in,
                              void* d_out, int out_size, void* d_ws, size_t ws_size,
                              hipStream_t stream) {
    const float* AB = (const float*)d_in[0];  // vol_AB
    const float* BA = (const float*)d_in[1];  // vol_BA
    const float* BC = (const float*)d_in[2];  // vol_BC
    const float* CB = (const float*)d_in[3];  // vol_CB
    const float* AC = (const float*)d_in[4];  // vol_AC
    const float* CA = (const float*)d_in[5];  // vol_CA
    // d_in[6..8] (xy/yz/xz rel ids) are unused by the reference.

    const unsigned nElems = (unsigned)in_sizes[0];  // N*2 = 16M
    const int block = 256;
    // grid 2560 = 10 blocks/CU of work; residency (3-5 blocks/CU, set by
    // final VGPR count) is smoothed by staggered block completion.
    // 8 taps/thread -> 4 ring rounds, 6/8 taps fully pipelined.
    const int grid = 2560;

    // d_out is poisoned with 0xAA before every timed launch — zero it.
    hipMemsetAsync(d_out, 0, (size_t)out_size * sizeof(float), stream);
    box_loss_kernel<<<grid, block, 0, stream>>>(AB, BA, BC, CB, AC, CA,
                                                (float*)d_out, nElems);
}